// Round 12
// baseline (139.327 us; speedup 1.0000x reference)
//
#include <hip/hip_runtime.h>
#include <hip/hip_fp16.h>

typedef unsigned long long u64;
typedef unsigned int u32;
typedef float float4a __attribute__((ext_vector_type(4), aligned(4)));

// Problem constants (setup_inputs: B=8, Hs=Ws=256, H=W=512, niter=5)
#define B_    8
#define HS_   256
#define WS_   256
#define H_    512
#define W_    512
#define HW_   (H_ * W_)
#define TO_Y  16                 // output rows per block
#define WR    36                 // window rows = TO_Y + 2*10
#define WCOLS 276                // window cols = 256 + 2*10
#define WSTR  277                // LDS plane stride (odd -> rotates banks)
#define NBAND 32                 // 16-row bands per batch
#define NBKT  64                 // buckets per batch = band*2 + xhalf
#define INFW  0xFFFFFFFFu
#define CAPB  8192               // bucket capacity (expected ~4.4K, ~2x margin)

// ---------------------------------------------------------------------------
// Bilinear upsample of (src - base), bit-exact vs the numpy reference
// (contraction off; same op order). Pixel PAIRS load as float4 (16 B).
// x0==255 (only output col 511, wx==0): shift pair to (254,255), weights
// (0,1) — identical result.
// ---------------------------------------------------------------------------
__device__ __forceinline__ void bilin_disp(const float* __restrict__ src,
                                           const float* __restrict__ base,
                                           int b, int y, int x,
                                           float& dx, float& dy) {
#pragma clang fp contract(off)
    float cy = ((float)y + 0.5f) * 0.5f - 0.5f;
    cy = fminf(fmaxf(cy, 0.0f), 255.0f);
    int   y0 = (int)floorf(cy);
    int   y1 = min(y0 + 1, HS_ - 1);
    float wy = cy - (float)y0;

    float cx = ((float)x + 0.5f) * 0.5f - 0.5f;
    cx = fminf(fmaxf(cx, 0.0f), 255.0f);
    int   x0 = (int)floorf(cx);
    float wx = cx - (float)x0;

    float omy = 1.0f - wy;
    float wA, wB;
    int xs;
    if (x0 >= WS_ - 1) { xs = WS_ - 2; wA = 0.0f; wB = 1.0f; }
    else               { xs = x0;      wA = 1.0f - wx; wB = wx; }

    const float4a* S0 = (const float4a*)(src  + ((b * HS_ + y0) * WS_ + xs) * 2);
    const float4a* S1 = (const float4a*)(src  + ((b * HS_ + y1) * WS_ + xs) * 2);
    const float4a* B0 = (const float4a*)(base + (y0 * WS_ + xs) * 2);
    const float4a* B1 = (const float4a*)(base + (y1 * WS_ + xs) * 2);
    float4a s0 = *S0, s1 = *S1, b0 = *B0, b1 = *B1;

    float a00x = s0.x - b0.x, a00y = s0.y - b0.y;
    float a01x = s0.z - b0.z, a01y = s0.w - b0.w;
    float a10x = s1.x - b1.x, a10y = s1.y - b1.y;
    float a11x = s1.z - b1.z, a11y = s1.w - b1.w;

    float r0x = a00x * omy + a10x * wy;   // blend along y first (matches ref)
    float r0y = a00y * omy + a10y * wy;
    float r1x = a01x * omy + a11x * wy;
    float r1y = a01y * omy + a11y * wy;
    dx = (r0x * wA + r1x * wB) * 256.0f;  // * (W/2), exact pow2
    dy = (r0y * wA + r1y * wB) * 256.0f;
}

__device__ __forceinline__ u32 pack16(float x, float y) {
    __half hx = __float2half_rn(x), hy = __float2half_rn(y);
    return ((u32)__half_as_ushort(hy) << 16) | (u32)__half_as_ushort(hx);
}
__device__ __forceinline__ float2 unpack16(u32 p) {
    float2 f;
    f.x = __half2float(__ushort_as_half((unsigned short)(p & 0xFFFFu)));
    f.y = __half2float(__ushort_as_half((unsigned short)(p >> 16)));
    return f;
}

__device__ __forceinline__ u64 shfl_left(u64 v) {
    unsigned lo = __shfl_up((unsigned)v, 1);
    unsigned hi = __shfl_up((unsigned)(v >> 32), 1);
    u64 r = ((u64)hi << 32) | lo;
    return (threadIdx.x & 63) ? r : 0ull;
}
__device__ __forceinline__ u64 shfl_right(u64 v) {
    unsigned lo = __shfl_down((unsigned)v, 1);
    unsigned hi = __shfl_down((unsigned)(v >> 32), 1);
    u64 r = ((u64)hi << 32) | lo;
    return ((threadIdx.x & 63) == 63) ? 0ull : r;
}

// ---------------------------------------------------------------------------
// Pass 1: evaluate every source ONCE (bit-exact decisions), append u64 entry
//   e = j<<46 | (yi&15)<<42 | xi<<33 | half2(-dx,-dy)        (bit 32 = 0)
// into bucket[b][band*2 + (xi>>8)]. j in the MSBs => u64 min == min-j ==
// reference winner; payload rides along so NOTHING is gathered downstream.
// Entries with xi in the boundary sliver [246,265] are duplicated into the
// neighboring x-half's bucket (consumer windows then need no xi filtering).
// Ranks via WAVE-BALLOT aggregation: one LDS atomicAdd per distinct bucket
// per wave (~6) instead of 1024 serialized same-address atomics (the R9-R11
// pre_k stall). bid&7 = batch -> XCD pin (round-robin heuristic).
// ---------------------------------------------------------------------------
__launch_bounds__(1024)
__global__ void pre_k(const float* __restrict__ src,
                      const float* __restrict__ base,
                      u32* __restrict__ gcount,
                      u64* __restrict__ bucket) {
    __shared__ u32 cnt[NBKT];
    __shared__ u32 bbase[NBKT];

    int bid  = blockIdx.x;
    int b    = bid & 7;
    int t    = bid >> 3;                   // 0..255 (2 source rows per block)
    int j    = t * 1024 + threadIdx.x;     // per-batch source index
    int y    = j >> 9;
    int x    = j & (W_ - 1);
    int lane = threadIdx.x & 63;
    u64 lmlt = ((u64)1 << lane) - 1;

    if (threadIdx.x < NBKT) cnt[threadIdx.x] = 0;
    __syncthreads();

    float dx, dy;
    bilin_disp(src, base, b, y, x, dx, dy);

    int xi = (int)rintf((float)x + dx);    // round-half-even == jnp.round
    int yi = (int)rintf((float)y + dy);
    bool inb = (xi >= 0 && xi < W_ && yi >= 0 && yi < H_);
    int bk0 = 0, bk1 = -1;
    u32 rank0 = 0, rank1 = 0;
    u64 e = 0;
    if (inb) {
        int band = yi >> 4;
        bk0 = band * 2 + (xi >> 8);
        if      (xi >= 246 && xi <= 255) bk1 = band * 2 + 1;
        else if (xi >= 256 && xi <= 265) bk1 = band * 2;
        e = ((u64)(u32)j << 46) | ((u64)(u32)(yi & 15) << 42)
          | ((u64)(u32)xi << 33) | (u64)pack16(-dx, -dy);
    }

    // wave-aggregated rank assignment for bk0
    u64 act = __ballot(inb);
    while (act) {
        int ldr = __builtin_ctzll(act);
        int bq  = __shfl(bk0, ldr, 64);
        u64 same = __ballot(inb && (bk0 == bq));
        u32 basev = 0;
        if (lane == ldr)
            basev = atomicAdd(&cnt[bq], (u32)__builtin_popcountll(same));
        basev = __shfl(basev, ldr, 64);
        if (inb && bk0 == bq)
            rank0 = basev + (u32)__builtin_popcountll(same & lmlt);
        act &= ~same;
    }
    if (bk1 >= 0) rank1 = atomicAdd(&cnt[bk1], 1u);   // rare (~4% of lanes)
    __syncthreads();

    if (threadIdx.x < NBKT) {
        u32 c = cnt[threadIdx.x];
        bbase[threadIdx.x] = c ? atomicAdd(&gcount[b * NBKT + threadIdx.x], c)
                               : 0u;
    }
    __syncthreads();

    if (inb) {
        u32 s0 = bbase[bk0] + rank0;
        if (s0 < CAPB) bucket[(b * NBKT + bk0) * CAPB + s0] = e;
        if (bk1 >= 0) {
            u32 s1 = bbase[bk1] + rank1;
            if (s1 < CAPB) bucket[(b * NBKT + bk1) * CAPB + s1] = e;
        }
    }
}

// ---------------------------------------------------------------------------
// Pass 2: fused bucket-scatter (key+payload in one u64 LDS atomicMin) +
// in-place u64->u32 compaction + 5x diffusion + 5x erosion + compose.
// 512 blocks = 32 row-tiles x 2 x-halves x 8 batches (id&7 = batch -> XCD
// pin); 512 threads = 8 waves = the 8 column slices. u64 plane 36 x 277
// (79.8 KB) -> 2 blocks/CU. vs R11: the scattered pay-gather phase (~300 MB
// amplified L2 traffic) is GONE — the winner entry already carries its
// payload.
//
// Empty slot = ~0ull (hi 0xFFFFFFFF; real entries' hi <= 0xFFFFFFFE).
// Compaction writes 0 for empty cells (finite, R6 NaN lesson) and the
// payload lo-word otherwise; reg-staged with barriers (writes at byte 4i
// overlap other threads' unread u64 cells otherwise).
//
// Stencil geometry identical to verified R7-R11 (lane = column, 32-col
// output slice + 16-lane halos; u64 bitmask over WR=36 rows): mask exact at
// ring>=5 after 5 dilations, >=10 after 5 erosions = output (bits 10..25,
// lanes 16..47); value updates restricted to bits 6..29 x lanes 6..57;
// zero-value contamination capped at ring 9 < 10; validm pins
// out-of-padded-array cells unmasked (True-pad erosion rule never fires).
// In-place value safety: writers have old-mask 0, readers read old-mask-1
// cells (disjoint); barrier between iterations.
// ---------------------------------------------------------------------------
__launch_bounds__(512, 2)
__global__ void fused6_k(const u32* __restrict__ gcount,
                         const u64* __restrict__ bucket,
                         const float* __restrict__ kern,
                         const float* __restrict__ tgt,
                         float* __restrict__ out) {
    __shared__ u64 plane[WR * WSTR];       // 79776 B
    u32* vals = (u32*)plane;               // post-compaction u32 plane

    int id   = blockIdx.x;                 // 0..511
    int b    = id & 7;                     // batch == XCD (round-robin pin)
    int rest = id >> 3;                    // 0..63
    int tile = rest >> 1;                  // 0..31
    int half = rest & 1;
    int X0   = half << 8;
    int Y0   = tile * TO_Y;
    int w0   = Y0 - 10;                    // window row 0 (output coords)
    int wc0  = X0 - 10;                    // window col 0 (output coords)
    int tid  = threadIdx.x;

    float kw[9];
#pragma unroll
    for (int q = 0; q < 9; q++) kw[q] = kern[q];

    // ---- phase 0: init ----
    for (int i = tid; i < WR * WSTR; i += 512) plane[i] = ~0ull;
    __syncthreads();

    // ---- phase 1: scatter entries from this half's 2-3 band buckets ----
    {
        int qlo = max(0, w0 >> 4);
        int qhi = min(NBAND - 1, (w0 + WR - 1) >> 4);
        for (int q = qlo; q <= qhi; q++) {
            int bki = b * NBKT + q * 2 + half;
            u32 cntq = min(gcount[bki], (u32)CAPB);
            const u64* bk = bucket + (size_t)bki * CAPB;
            int ybase = q * 16 - w0;       // band row 0 in window coords
            for (u32 i = tid; i < cntq; i += 512) {
                u64 e  = bk[i];
                int wr = ybase + (int)((e >> 42) & 15u);
                if ((unsigned)wr < WR) {
                    int xc = (int)((e >> 33) & 511u) - wc0;  // in [0,275]
                    atomicMin(&plane[wr * WSTR + xc], e);
                }
            }
        }
    }
    __syncthreads();

    // ---- phase 2a: per-lane column mask (hi words) + stage compaction ----
    int wv   = tid >> 6;
    int lane = tid & 63;
    int col  = X0 + 32 * wv - 16 + lane;   // output-coord column of this lane
    int cls  = col - wc0;                  // plane column index
    bool inwin = ((unsigned)cls < WCOLS);
    bool colin = inwin && (col >= -6) && (col <= W_ + 5);  // padded [-6,517]

    u64 m = 0;
    if (colin) {
#pragma unroll 6
        for (int r = 0; r < WR; r++)
            m |= (u64)(((const u32*)plane)[(r * WSTR + cls) * 2 + 1] != INFW) << r;
    }

    u32 regs[20];
#pragma unroll
    for (int k = 0; k < 20; k++) {
        int idx = tid + k * 512;
        if (idx < WR * WCOLS) {
            int rr = idx / WCOLS;
            int cc = idx - rr * WCOLS;
            u64 v = plane[rr * WSTR + cc];
            regs[k] = ((u32)(v >> 32) == INFW) ? 0u : (u32)v;
        }
    }
    __syncthreads();

    // ---- phase 2b: write compacted u32 value plane ----
#pragma unroll
    for (int k = 0; k < 20; k++) {
        int idx = tid + k * 512;
        if (idx < WR * WCOLS) {
            int rr = idx / WCOLS;
            int cc = idx - rr * WCOLS;
            vals[rr * WSTR + cc] = regs[k];
        }
    }
    __syncthreads();

    int rlo = max(0, -6 - w0);
    int rhi = min(WR - 1, (W_ + 5) - w0);
    u64 validm = colin ? ((((u64)1 << (rhi - rlo + 1)) - 1) << rlo) : 0ull;

    const u64 VROWS = (((u64)1 << 24) - 1) << 6;   // bits 6..29
    bool vlane = (lane >= 6 && lane <= 57);

    // ---- phase 3: 5 diffusion iterations ----
    for (int it = 0; it < 5; it++) {
        u64 mL = shfl_left(m), mR = shfl_right(m);
        u64 cand = ~m & ((m << 1) | (m >> 1) | mL | mR) & validm;
        u64 cv = vlane ? (cand & VROWS) : 0ull;
        while (cv) {
            int r = __builtin_ctzll(cv);
            cv &= cv - 1;
            float s = 0.0f, ax = 0.0f, ay = 0.0f;
#pragma unroll
            for (int dr = -1; dr <= 1; dr++) {
#pragma unroll
                for (int dc = -1; dc <= 1; dc++) {
                    if (dr == 0 && dc == 0) continue;
                    u64 nm = (dc < 0) ? mL : ((dc > 0) ? mR : m);
                    float wq = ((nm >> (r + dr)) & 1)
                                 ? kw[(dr + 1) * 3 + (dc + 1)] : 0.0f;
                    int cc = min(max(cls + dc, 0), WCOLS - 1); // clamp: wq==0
                    float2 nv = unpack16(vals[(r + dr) * WSTR + cc]);
                    s += wq; ax += wq * nv.x; ay += wq * nv.y;
                }
            }
            float rs = __builtin_amdgcn_rcpf(s);   // ~1e-7 rel err, in tol
            vals[r * WSTR + cls] = pack16(ax * rs, ay * rs);
        }
        m |= cand;
        __syncthreads();
    }

    // ---- phase 4: 5 erosion iterations (registers only) + compose ----
    for (int it = 0; it < 5; it++) {
        u64 mL = shfl_left(m), mR = shfl_right(m);
        m &= (m << 1) & (m >> 1) & mL & mR;
    }

    if (lane >= 16 && lane < 48) {
#pragma unroll 4
        for (int r = 10; r < 10 + TO_Y; r++) {
            int row = w0 + r;              // Y0 .. Y0+15, always in [0,512)
            bool on = (m >> r) & 1;
            float vx, vy;
            if (on) {
                float2 t = unpack16(vals[r * WSTR + cls]);
                vx = t.x * (1.0f / 256.0f);   // 2/W exact
                vy = t.y * (1.0f / 256.0f);   // 2/H exact
            } else {
                vx = 4.0f; vy = 4.0f;
            }
            int ti = (row * W_ + col) * 2;
            float2 tg = *(const float2*)(tgt + ti);
            float2 ov; ov.x = tg.x + vx; ov.y = tg.y + vy;
            ((float2*)out)[(size_t)b * HW_ + row * W_ + col] = ov;
        }
    }
}

extern "C" void kernel_launch(void* const* d_in, const int* in_sizes, int n_in,
                              void* d_out, int out_size, void* d_ws, size_t ws_size,
                              hipStream_t stream) {
    const float* src  = (const float*)d_in[0];  // (8,256,256,2)
    const float* kern = (const float*)d_in[1];  // (3,3)
    const float* base = (const float*)d_in[2];  // (1,256,256,2)
    const float* tgt  = (const float*)d_in[3];  // (1,512,512,2)
    float* out = (float*)d_out;                 // (8,512,512,2)

    char* ws = (char*)d_ws;
    u32* gcount = (u32*)ws;                     // 2 KB (padded to 4 KB)
    u64* bucket = (u64*)(ws + 4096);            // 33.6 MB

    hipMemsetAsync(gcount, 0, B_ * NBKT * sizeof(u32), stream);

    pre_k<<<(B_ * HW_) / 1024, 1024, 0, stream>>>(src, base, gcount, bucket);
    fused6_k<<<512, 512, 0, stream>>>(gcount, bucket, kern, tgt, out);
}